// Round 3
// baseline (231.489 us; speedup 1.0000x reference)
//
#include <hip/hip_runtime.h>

// SpanRepresentation flat-streaming rewrite (R2: native vector type for NT stores).
// out[b,s,:] = concat(x[b,start(s),:], x[b,start(s)+w(s)-1,:], wemb[bucket(w),:])
// B=8, L=512, D=768(=192 f4), WDIM=20(=5 f4), S=4068, row=389 f4.

typedef float f4 __attribute__((ext_vector_type(4)));

#define D4      192
#define S_TOT   4068
#define ROW4    389
#define TOTAL4  (8 * S_TOT * ROW4)   // 12,659,616 float4 (202.6 MB)

__device__ __forceinline__ const f4* span_src(
    int j, const f4* __restrict__ x, const f4* __restrict__ we)
{
    unsigned row = (unsigned)j / ROW4;          // magic-mul (j < 2^24)
    int col = j - (int)row * ROW4;              // 0..388
    unsigned b = row / S_TOT;                   // 0..7
    int s = (int)row - (int)(b * S_TOT);

    // width-group decode: cumulative starts c[w] = {0,512,1023,1533,2042,2550,3057,3563}
    int w = 1, cw = 0;
    if (s >= 512)  { w = 2; cw = 512;  }
    if (s >= 1023) { w = 3; cw = 1023; }
    if (s >= 1533) { w = 4; cw = 1533; }
    if (s >= 2042) { w = 5; cw = 2042; }
    if (s >= 2550) { w = 6; cw = 2550; }
    if (s >= 3057) { w = 7; cw = 3057; }
    if (s >= 3563) { w = 8; cw = 3563; }
    const int start = s - cw;

    if (col < 2 * D4) {
        int r = (col < D4) ? start : (start + w - 1);
        int c = (col < D4) ? col : (col - D4);
        return x + ((b * 512u + (unsigned)r) * (unsigned)D4 + (unsigned)c);
    } else {
        // bucket(w) for w=1..8 -> {1,2,3,4,5,5,6,7}, nibble-packed
        int bucket = (int)((0x765543210ull >> (4 * w)) & 0xF);
        return we + bucket * 5 + (col - 2 * D4);
    }
}

__global__ __launch_bounds__(256) void span_rep_flat(
    const f4* __restrict__ x,
    const f4* __restrict__ we,
    f4* __restrict__ out)
{
    const int stride = gridDim.x * 256;
    int idx = blockIdx.x * 256 + (int)threadIdx.x;

    for (; idx < TOTAL4; idx += 4 * stride) {
        const int j1 = idx + stride;
        const int j2 = idx + 2 * stride;
        const int j3 = idx + 3 * stride;
        const bool p1 = j1 < TOTAL4;
        const bool p2 = j2 < TOTAL4;
        const bool p3 = j3 < TOTAL4;

        // Issue all independent loads first (MLP), then stream the stores.
        f4 v0 = *span_src(idx, x, we);
        f4 v1 = {}, v2 = {}, v3 = {};
        if (p1) v1 = *span_src(j1, x, we);
        if (p2) v2 = *span_src(j2, x, we);
        if (p3) v3 = *span_src(j3, x, we);

        __builtin_nontemporal_store(v0, &out[idx]);
        if (p1) __builtin_nontemporal_store(v1, &out[j1]);
        if (p2) __builtin_nontemporal_store(v2, &out[j2]);
        if (p3) __builtin_nontemporal_store(v3, &out[j3]);
    }
}

extern "C" void kernel_launch(void* const* d_in, const int* in_sizes, int n_in,
                              void* d_out, int out_size, void* d_ws, size_t ws_size,
                              hipStream_t stream) {
    const f4* x  = (const f4*)d_in[0];  // (8, 512, 768) f32 -> f4
    const f4* we = (const f4*)d_in[1];  // (14, 20) f32 -> f4 (5 per row)
    f4* out = (f4*)d_out;               // (8, 4068, 1556) f32 -> flat f4

    // 2048 blocks = 8 blocks/CU; 4-way unrolled grid-stride covers TOTAL4.
    span_rep_flat<<<2048, 256, 0, stream>>>(x, we, out);
}

// Round 4
// 209.649 us; speedup vs baseline: 1.1042x; 1.1042x over previous
//
#include <hip/hip_runtime.h>

// SpanRepresentation, broadcast-structured:
// each x-row x[b,r] (3 KB) appears in out exactly 16 times:
//   start-role for w=1..8: out[b, c_w + r,          0:768]  (valid iff r+w <= 512)
//   end-role   for w=1..8: out[b, c_w + r - w + 1, 768:1536] (valid iff r >= w-1)
// One block per (b,r): read row once into regs, stream up to 16 coalesced
// 3 KB stores. Wave 3 writes the 20-float wemb tail for the 8 spans that
// START at r (covers every (b,s) exactly once).

typedef float f4 __attribute__((ext_vector_type(4)));

#define L_DIM 512
#define S_TOT 4068
#define ROW4  389   // 1556 floats / 4
#define D4    192   // 768 floats / 4

__global__ __launch_bounds__(256) void span_rep_bcast(
    const f4* __restrict__ x,
    const f4* __restrict__ we,
    f4* __restrict__ out)
{
    const int r = blockIdx.x;   // x row 0..511
    const int b = blockIdx.y;   // batch 0..7
    const int t = (int)threadIdx.x;

    // cumulative span-group starts c_w for w=1..8
    const int cw[8] = {0, 512, 1023, 1533, 2042, 2550, 3057, 3563};

    const size_t outB = (size_t)b * S_TOT;

    if (t < 192) {
        // one coalesced float4 load; 192 threads cover the 768-float row
        const f4 v = x[((size_t)b * L_DIM + r) * D4 + t];
        #pragma unroll
        for (int w = 1; w <= 8; ++w) {
            if (r + w <= L_DIM)   // start-role: span (start=r, width=w)
                out[(outB + cw[w - 1] + r) * ROW4 + t] = v;
            if (r >= w - 1)       // end-role: span (start=r-w+1, width=w)
                out[(outB + cw[w - 1] + r - w + 1) * ROW4 + D4 + t] = v;
        }
    } else {
        // wave 3: wemb tail (5 f4) for the up-to-8 spans starting at r
        const int u = t - 192;
        if (u < 40) {
            const int w = u / 5 + 1;          // 1..8
            const int col = u - (w - 1) * 5;  // 0..4
            if (r + w <= L_DIM) {
                const int bucket = (int)((0x765543210ull >> (4 * w)) & 0xF);
                out[(outB + cw[w - 1] + r) * ROW4 + 2 * D4 + col] = we[bucket * 5 + col];
            }
        }
    }
}

extern "C" void kernel_launch(void* const* d_in, const int* in_sizes, int n_in,
                              void* d_out, int out_size, void* d_ws, size_t ws_size,
                              hipStream_t stream) {
    const f4* x  = (const f4*)d_in[0];  // (8, 512, 768) f32
    const f4* we = (const f4*)d_in[1];  // (14, 20) f32, row = 5 f4 (16B-aligned)
    f4* out = (f4*)d_out;               // (8, 4068, 1556) f32

    dim3 grid(L_DIM, 8);                // (r, b) = 4096 blocks
    span_rep_bcast<<<grid, 256, 0, stream>>>(x, we, out);
}